// Round 2
// baseline (261.118 us; speedup 1.0000x reference)
//
#include <hip/hip_runtime.h>
#include <stdint.h>

// Problem constants (match reference file)
#define B_ 8
#define C_ 256
#define N_ 16384
#define K_ 128

#define CT 64          // channels per block tile
#define PT 1024        // points per block
#define SUB 64         // points per LDS staging sub-tile
#define NSUB (PT / SUB)
#define TPAD 65        // row stride 65 floats == 1 bank -> 2-way (free) on both
                       // staging writes and transpose reads (m136: 2-way is free)

// Monotone float->uint key: preserves order under unsigned max.
// Any finite float maps to key > 0, so key==0 is the "empty segment" sentinel.
__device__ __forceinline__ unsigned f2key(float f) {
    unsigned u = __float_as_uint(f);
    return (u & 0x80000000u) ? ~u : (u | 0x80000000u);
}
__device__ __forceinline__ float key2f(unsigned k) {
    unsigned u = (k & 0x80000000u) ? (k & 0x7fffffffu) : ~k;
    return __uint_as_float(u);
}

__global__ __launch_bounds__(256, 2) void seghead_fused(
    const float* __restrict__ pf,     // [B][C][N]
    const int* __restrict__ cid,      // [B][N], values -1..K-1
    unsigned* __restrict__ gacc,      // [B*K][C] uint keys (aliases out0, pre-zeroed)
    float* __restrict__ out1)         // [B*N][C] transposed features
{
    __shared__ float tile[CT][TPAD];      // 16.25 KiB
    __shared__ unsigned acc[K_ * CT];     // 32 KiB   acc[cluster][ch_local]
    __shared__ int cids[PT];              // 4 KiB

    const int t = threadIdx.x;
    const int b = blockIdx.z;
    const int c0 = blockIdx.y * CT;
    const int n0 = blockIdx.x * PT;

    // init local accumulator to sentinel 0
    for (int i = t; i < K_ * CT; i += 256) acc[i] = 0u;
    // stage this block's cluster ids (coalesced)
    for (int i = t; i < PT; i += 256) cids[i] = cid[b * N_ + n0 + i];
    __syncthreads();

    const int x4   = t & 15;   // point group (x4*4 .. x4*4+3)
    const int cy   = t >> 4;   // 0..15
    const int lane = t & 63;
    const int w    = t >> 6;   // wave id 0..3

    for (int s = 0; s < NSUB; ++s) {
        const int nb = n0 + s * SUB;

        // ---- load 64ch x 64pt sub-tile, coalesced along N (float4 global) ----
        const float* src = pf + ((size_t)b * C_ + c0) * N_ + nb;
        #pragma unroll
        for (int r = 0; r < 4; ++r) {
            const int c = r * 16 + cy;
            float4 v = *(const float4*)(src + (size_t)c * N_ + x4 * 4);
            // scalar LDS stores (odd stride 65 forbids aligned float4):
            // bank = (c*65 + x4*4 + j) % 32 -> 2-way across a wave, free
            tile[c][x4 * 4 + 0] = v.x;
            tile[c][x4 * 4 + 1] = v.y;
            tile[c][x4 * 4 + 2] = v.z;
            tile[c][x4 * 4 + 3] = v.w;
        }
        __syncthreads();

        // ---- transposed write + LDS segment-max ----
        // wave w owns points nl = w*16 .. w*16+15; lane = channel within tile
        #pragma unroll
        for (int q = 0; q < 16; ++q) {
            const int nl = w * 16 + q;
            const float v = tile[lane][nl];   // bank (lane+nl)%32: 2-way, free
            out1[((size_t)b * N_ + nb + nl) * C_ + c0 + lane] = v;  // 256B/wave coalesced
            const int cc = cids[s * SUB + nl];  // wave-uniform
            if (cc >= 0) atomicMax(&acc[cc * CT + lane], f2key(v));
        }
        __syncthreads();
    }

    // ---- flush block-local maxima to global keys (skip empty entries) ----
    for (int i = t; i < K_ * CT; i += 256) {
        const unsigned k = acc[i];
        if (k) {
            const int cl = i >> 6;          // cluster
            const int ch = i & (CT - 1);    // local channel
            atomicMax(&gacc[(size_t)(b * K_ + cl) * C_ + c0 + ch], k);
        }
    }
}

// Decode keys in-place: key==0 (empty segment) -> 0.0f
__global__ void seghead_finalize(unsigned* __restrict__ gacc) {
    const int i = blockIdx.x * 256 + threadIdx.x;
    const unsigned k = gacc[i];
    ((float*)gacc)[i] = k ? key2f(k) : 0.0f;
}

extern "C" void kernel_launch(void* const* d_in, const int* in_sizes, int n_in,
                              void* d_out, int out_size, void* d_ws, size_t ws_size,
                              hipStream_t stream) {
    const float* pf  = (const float*)d_in[0];
    const int*   cid = (const int*)d_in[1];

    float*    out  = (float*)d_out;
    unsigned* gacc = (unsigned*)d_out;                      // out0 region reused as key accumulator
    float*    out1 = out + (size_t)B_ * K_ * C_;            // transposed features follow

    // zero the key accumulator (sentinel; harness re-poisons d_out each replay)
    hipMemsetAsync(d_out, 0, (size_t)B_ * K_ * C_ * sizeof(unsigned), stream);

    dim3 grid(N_ / PT, C_ / CT, B_);
    seghead_fused<<<grid, 256, 0, stream>>>(pf, cid, gacc, out1);

    seghead_finalize<<<(B_ * K_ * C_) / 256, 256, 0, stream>>>(gacc);
}